// Round 11
// baseline (88.043 us; speedup 1.0000x reference)
//
#include <hip/hip_runtime.h>
#include <hip/hip_fp16.h>

// NonAutoregressiveDecoder: K=1024, H=128, fp32 I/O.
// out = (coords_pred [1024,2], adj_logits [1024,1024]) flat-concat.

#define KN 1024
#define HN 128

typedef float  floatx4 __attribute__((ext_vector_type(4)));
typedef _Float16 half8v __attribute__((ext_vector_type(8)));

// f32 GELU (tanh form, log2e folded): x / (1 + exp2(x*(-2.3022087 - 0.1029434 x^2)))
__device__ __forceinline__ float gelu_f(float x) {
    float x2 = x * x;
    float t  = fmaf(x2, -0.1029434f, -2.3022087f);
    float e  = __builtin_amdgcn_exp2f(x * t);
    return x * __builtin_amdgcn_rcpf(e + 1.0f);
}

// packed-f16 GELU on 2 elements held in a uint
__device__ __forceinline__ unsigned int gelu2u(unsigned int xu) {
    __half2 x  = __builtin_bit_cast(__half2, xu);
    __half2 x2 = __hmul2(x, x);
    __half2 t  = __hfma2(x2, __float2half2_rn(-0.1029434f),
                             __float2half2_rn(-2.3022087f));
    __half2 e  = h2exp2(__hmul2(x, t));
    __half2 r  = h2rcp(__hadd2(e, __float2half2_rn(1.0f)));
    return __builtin_bit_cast(unsigned int, __hmul2(x, r));
}

__device__ __forceinline__ unsigned int cvt2u(float a, float b) {
    return __builtin_bit_cast(unsigned int, __builtin_amdgcn_cvt_pkrtz(a, b));
}

// gelu(h2-slots) -> second-MFMA dot with w3: returns adj value (row 0 of D)
__device__ __forceinline__ float dotw3(const floatx4* acc, half8v w3f0,
                                       half8v w3f1, float b3) {
    uint4 u0, u1;
    u0.x = gelu2u(cvt2u(acc[0][0], acc[0][1]));
    u0.y = gelu2u(cvt2u(acc[0][2], acc[0][3]));
    u0.z = gelu2u(cvt2u(acc[1][0], acc[1][1]));
    u0.w = gelu2u(cvt2u(acc[1][2], acc[1][3]));
    u1.x = gelu2u(cvt2u(acc[2][0], acc[2][1]));
    u1.y = gelu2u(cvt2u(acc[2][2], acc[2][3]));
    u1.z = gelu2u(cvt2u(acc[3][0], acc[3][1]));
    u1.w = gelu2u(cvt2u(acc[3][2], acc[3][3]));
    half8v h20 = __builtin_bit_cast(half8v, u0);
    half8v h21 = __builtin_bit_cast(half8v, u1);
    floatx4 d = (floatx4){b3, b3, b3, b3};
    d = __builtin_amdgcn_mfma_f32_16x16x32_f16(w3f0, h20, d, 0, 0, 0);
    d = __builtin_amdgcn_mfma_f32_16x16x32_f16(w3f1, h21, d, 0, 0, 0);
    return d[0];
}

// ---------------- Kernel A: pi' = z@eW1[:H]+eb1 (f16), pj = z@eW1[H:] (f16),
//   coords -> d_out, w2T (f16, dim-PERMUTED transpose of eW2), w3h (f16 eW3) --
// 256 blocks x 256 thr, 4 rows/block (full CU coverage).
// w2T row R(d) = 32*(d>>5)+16*((d>>2)&1)+4*((d>>3)&3)+(d&3).
__global__ __launch_bounds__(256) void prep_kernel(
    const float* __restrict__ z,   const float* __restrict__ cW1,
    const float* __restrict__ cb1, const float* __restrict__ cW2,
    const float* __restrict__ cb2, const float* __restrict__ eW1,
    const float* __restrict__ eb1, const float* __restrict__ eW2,
    const float* __restrict__ eW3,
    _Float16* __restrict__ pi_h,   _Float16* __restrict__ pj_h,
    _Float16* __restrict__ w2T,    _Float16* __restrict__ w3h,
    float* __restrict__ coords /* = d_out */) {
    __shared__ float z4[4][128];
    __shared__ float c1s[4][64];
    const int tid = threadIdx.x;
    const int r0  = blockIdx.x * 4;

    // w2T fill (permuted rows): blocks 0..31, 256 elems each.
    if (blockIdx.x < 32) {
        int e = blockIdx.x * 256 + tid;          // e = d*128 + k
        int d = e >> 7, k = e & 127;
        int R = ((d >> 5) & 1) * 32 + ((d >> 2) & 1) * 16 +
                ((d >> 3) & 3) * 4  + (d & 3);
        w2T[R * 128 + k] = (_Float16)eW2[k * 64 + d];
    }
    if (blockIdx.x == 32 && tid < 64) w3h[tid] = (_Float16)eW3[tid];

#pragma unroll
    for (int s = 0; s < 2; ++s) {
        int e = tid + 256 * s;                   // 0..511
        z4[e >> 7][e & 127] = z[r0 * HN + e];
    }
    __syncthreads();

    const int col = tid & 127, which = tid >> 7;   // 0 = pi, 1 = pj
    const float* w = eW1 + which * HN * HN + col;
    float acc4[4] = {0.f, 0.f, 0.f, 0.f};
    for (int k = 0; k < HN; ++k) {
        float wv = w[k * HN];
#pragma unroll
        for (int r = 0; r < 4; ++r) acc4[r] = fmaf(z4[r][k], wv, acc4[r]);
    }
    if (which == 0) {
        float b = eb1[col];
#pragma unroll
        for (int r = 0; r < 4; ++r)
            pi_h[(r0 + r) * HN + col] = (_Float16)(acc4[r] + b);
    } else {
#pragma unroll
        for (int r = 0; r < 4; ++r)
            pj_h[(r0 + r) * HN + col] = (_Float16)acc4[r];
    }

    // coords: c1 = gelu(z @ cW1 + cb1), coords = c1 @ cW2 + cb2
    {
        int row = tid >> 6, mid = tid & 63;      // 256 tasks = 4 rows x 64 mids
        float a = cb1[mid];
        for (int k = 0; k < HN; ++k) a = fmaf(z4[row][k], cW1[k * 64 + mid], a);
        c1s[row][mid] = gelu_f(a);
    }
    __syncthreads();
    if (tid < 8) {
        int row = tid >> 1, o = tid & 1;
        float a = cb2[o];
#pragma unroll 8
        for (int m = 0; m < 64; ++m) a = fmaf(c1s[row][m], cW2[m * 2 + o], a);
        coords[(r0 + row) * 2 + o] = a;
    }
}

// ---------------- Kernel B: fused h1->h2->adj_raw over a 32x16 (i,j) tile ----
// 512 threads (8 waves), each wave does 4 i-rows x 16 j. Single j-subtile:
// per-wave persistent state ~55 arch VGPR + 16 acc -> fits (512,6) budget of
// 85/wave -> 6 waves/SIMD (3 blocks/CU) to fill the 34% VALU-idle seen at
// (512,4). ONLY w2 lives in LDS (16 KB); pi rows wave-uniform L1-hot global
// reads; pj fragments global->registers once.
__global__ __launch_bounds__(512, 6) void edge_kernel(
    const _Float16* __restrict__ pi_h, const _Float16* __restrict__ pj_h,
    const _Float16* __restrict__ w2T,  const _Float16* __restrict__ w3h,
    const float* __restrict__ eb2,     const float* __restrict__ eb3,
    float* __restrict__ out_adj) {
    __shared__ __align__(16) unsigned int w2_s[64 * 64];  // 16 KB [64 slots][64 dw]
    const int i0 = blockIdx.y * 32, j0 = blockIdx.x * 16;
    const int tid = threadIdx.x;

    const unsigned int* piu = (const unsigned int*)pi_h;   // [1024][64]
    const unsigned int* pju = (const unsigned int*)pj_h;
    const unsigned int* w2u = (const unsigned int*)w2T;    // [64][64]

    // stage w2 swizzled: dword ^= (row&7)<<2; 2 x dwordx4 per thread
#pragma unroll
    for (int s = 0; s < 2; ++s) {
        int e = tid * 4 + 2048 * s;       // dword idx, %4 == 0
        int r = e >> 6;
        uint4 v = *reinterpret_cast<const uint4*>(&w2u[e]);
        *reinterpret_cast<uint4*>(&w2_s[e ^ ((r & 7) << 2)]) = v;
    }

    const int lane = tid & 63;
    const int wave = tid >> 6;          // 0..7
    const int lrow = lane & 15;         // j within subtile / MFMA col
    const int lhi  = lane >> 4;         // k-slice group
    const int lhi4 = lhi << 2;
    const int lhi8 = lhi << 3;
    const int swzW = (lrow & 7) << 2;

    // pj fragments straight from global (t-invariant): 1 j-subtile x 4 q
    const unsigned int* pjA = &pju[(j0 + lrow) * 64];
    half8v bA[4];
#pragma unroll
    for (int q = 0; q < 4; ++q) {
        const int ko = (q << 4) | lhi4;
        bA[q] = *reinterpret_cast<const half8v*>(&pjA[ko]);
    }
    const unsigned int* w2base = &w2_s[lrow << 6];

    // w3 A-fragments and permuted-slot eb2 bias (lhi-dependent only)
    const half8v w3f0 = *reinterpret_cast<const half8v*>(&w3h[lhi8]);
    const half8v w3f1 = *reinterpret_cast<const half8v*>(&w3h[32 + lhi8]);
    const float4 e0 = *reinterpret_cast<const float4*>(&eb2[lhi8]);
    const float4 e1 = *reinterpret_cast<const float4*>(&eb2[lhi8 + 4]);
    const float4 e2 = *reinterpret_cast<const float4*>(&eb2[32 + lhi8]);
    const float4 e3 = *reinterpret_cast<const float4*>(&eb2[36 + lhi8]);
    const float b3 = eb3[0];
    __syncthreads();

#pragma unroll
    for (int t = 0; t < 4; ++t) {
        const int iL = (wave << 2) + t;             // 0..31
        const unsigned int* pirow = &piu[(size_t)(i0 + iL) * 64];

        floatx4 accA[4];
        accA[0] = (floatx4){e0.x, e0.y, e0.z, e0.w};
        accA[1] = (floatx4){e1.x, e1.y, e1.z, e1.w};
        accA[2] = (floatx4){e2.x, e2.y, e2.z, e2.w};
        accA[3] = (floatx4){e3.x, e3.y, e3.z, e3.w};

#pragma unroll
        for (int q = 0; q < 4; ++q) {
            const int ko = (q << 4) | lhi4;
            half8v a = *reinterpret_cast<const half8v*>(&pirow[ko]);  // global

            uint4 sA = __builtin_bit_cast(uint4, a + bA[q]);   // v_pk_add_f16
            uint4 gA;
            gA.x = gelu2u(sA.x); gA.y = gelu2u(sA.y);
            gA.z = gelu2u(sA.z); gA.w = gelu2u(sA.w);
            half8v afA = __builtin_bit_cast(half8v, gA);

            const int kw = ko ^ swzW;
#pragma unroll
            for (int c = 0; c < 4; ++c) {
                half8v bf = *reinterpret_cast<const half8v*>(
                    &w2base[(c << 10) + kw]);       // w2 slot-row c*16+lrow
                accA[c] = __builtin_amdgcn_mfma_f32_16x16x32_f16(
                    bf, afA, accA[c], 0, 0, 0);
            }
        }

        const float dA = dotw3(accA, w3f0, w3f1, b3);
        if (lhi == 0)
            out_adj[(size_t)(i0 + iL) * KN + j0 + lrow] = dA;
    }
}

// ---------------- Kernel C: in-place symmetrize ------------------------------
__global__ __launch_bounds__(256) void sym_kernel(float* __restrict__ adj) {
    int idx = blockIdx.x * 256 + threadIdx.x;
    int i = idx >> 10, j = idx & 1023;
    if (j < i) return;
    float a = adj[i * KN + j];
    float b = adj[j * KN + i];
    float m = 0.5f * (a + b);
    adj[i * KN + j] = m;
    adj[j * KN + i] = m;
}

extern "C" void kernel_launch(void* const* d_in, const int* in_sizes, int n_in,
                              void* d_out, int out_size, void* d_ws, size_t ws_size,
                              hipStream_t stream) {
    const float* z   = (const float*)d_in[0];
    const float* cW1 = (const float*)d_in[1];
    const float* cb1 = (const float*)d_in[2];
    const float* cW2 = (const float*)d_in[3];
    const float* cb2 = (const float*)d_in[4];
    const float* eW1 = (const float*)d_in[5];
    const float* eb1 = (const float*)d_in[6];
    const float* eW2 = (const float*)d_in[7];
    const float* eb2 = (const float*)d_in[8];
    const float* eW3 = (const float*)d_in[9];
    const float* eb3 = (const float*)d_in[10];

    float* out = (float*)d_out;
    _Float16* pi_h = (_Float16*)d_ws;            // [1024][128] f16
    _Float16* pj_h = pi_h + KN * HN;             // [1024][128] f16
    _Float16* w2T  = pj_h + KN * HN;             // [64][128]  f16 (permuted eW2^T)
    _Float16* w3h  = w2T + 64 * HN;              // [64]       f16

    prep_kernel<<<256, 256, 0, stream>>>(z, cW1, cb1, cW2, cb2, eW1, eb1, eW2,
                                         eW3, pi_h, pj_h, w2T, w3h, out);

    dim3 gridB(64, 32);   // x: 16-wide j tiles, y: 32-tall i tiles
    edge_kernel<<<gridB, 512, 0, stream>>>(pi_h, pj_h, w2T, w3h, eb2, eb3,
                                           out + 2048);

    sym_kernel<<<4096, 256, 0, stream>>>(out + 2048);
}

// Round 12
// 78.970 us; speedup vs baseline: 1.1149x; 1.1149x over previous
//
#include <hip/hip_runtime.h>
#include <hip/hip_fp16.h>

// NonAutoregressiveDecoder: K=1024, H=128, fp32 I/O.
// out = (coords_pred [1024,2], adj_logits [1024,1024]) flat-concat.

#define KN 1024
#define HN 128

typedef float  floatx4 __attribute__((ext_vector_type(4)));
typedef _Float16 half8v __attribute__((ext_vector_type(8)));

// f32 GELU (tanh form, log2e folded): x / (1 + exp2(x*(-2.3022087 - 0.1029434 x^2)))
__device__ __forceinline__ float gelu_f(float x) {
    float x2 = x * x;
    float t  = fmaf(x2, -0.1029434f, -2.3022087f);
    float e  = __builtin_amdgcn_exp2f(x * t);
    return x * __builtin_amdgcn_rcpf(e + 1.0f);
}

// packed-f16 GELU on 2 elements held in a uint
__device__ __forceinline__ unsigned int gelu2u(unsigned int xu) {
    __half2 x  = __builtin_bit_cast(__half2, xu);
    __half2 x2 = __hmul2(x, x);
    __half2 t  = __hfma2(x2, __float2half2_rn(-0.1029434f),
                             __float2half2_rn(-2.3022087f));
    __half2 e  = h2exp2(__hmul2(x, t));
    __half2 r  = h2rcp(__hadd2(e, __float2half2_rn(1.0f)));
    return __builtin_bit_cast(unsigned int, __hmul2(x, r));
}

__device__ __forceinline__ unsigned int cvt2u(float a, float b) {
    return __builtin_bit_cast(unsigned int, __builtin_amdgcn_cvt_pkrtz(a, b));
}

// gelu(h2-slots) -> second-MFMA dot with w3: returns adj value (row 0 of D).
// The two MFMAs accumulate independently (d0, d1) so they can overlap; the
// b3 bias and the two partial dots are summed in scalar f32 at the end.
__device__ __forceinline__ float dotw3(const floatx4* acc, half8v w3f0,
                                       half8v w3f1, float b3) {
    uint4 u0, u1;
    u0.x = gelu2u(cvt2u(acc[0][0], acc[0][1]));
    u0.y = gelu2u(cvt2u(acc[0][2], acc[0][3]));
    u0.z = gelu2u(cvt2u(acc[1][0], acc[1][1]));
    u0.w = gelu2u(cvt2u(acc[1][2], acc[1][3]));
    u1.x = gelu2u(cvt2u(acc[2][0], acc[2][1]));
    u1.y = gelu2u(cvt2u(acc[2][2], acc[2][3]));
    u1.z = gelu2u(cvt2u(acc[3][0], acc[3][1]));
    u1.w = gelu2u(cvt2u(acc[3][2], acc[3][3]));
    half8v h20 = __builtin_bit_cast(half8v, u0);
    half8v h21 = __builtin_bit_cast(half8v, u1);
    floatx4 z0 = (floatx4){0.f, 0.f, 0.f, 0.f};
    floatx4 z1 = (floatx4){0.f, 0.f, 0.f, 0.f};
    floatx4 d0 = __builtin_amdgcn_mfma_f32_16x16x32_f16(w3f0, h20, z0, 0, 0, 0);
    floatx4 d1 = __builtin_amdgcn_mfma_f32_16x16x32_f16(w3f1, h21, z1, 0, 0, 0);
    return d0[0] + d1[0] + b3;
}

// ---------------- Kernel A: pi' = z@eW1[:H]+eb1 (f16), pj = z@eW1[H:] (f16),
//   coords -> d_out, w2T (f16, dim-PERMUTED transpose of eW2), w3h (f16 eW3) --
// 256 blocks x 256 thr, 4 rows/block (full CU coverage).
// w2T row R(d) = 32*(d>>5)+16*((d>>2)&1)+4*((d>>3)&3)+(d&3).
__global__ __launch_bounds__(256) void prep_kernel(
    const float* __restrict__ z,   const float* __restrict__ cW1,
    const float* __restrict__ cb1, const float* __restrict__ cW2,
    const float* __restrict__ cb2, const float* __restrict__ eW1,
    const float* __restrict__ eb1, const float* __restrict__ eW2,
    const float* __restrict__ eW3,
    _Float16* __restrict__ pi_h,   _Float16* __restrict__ pj_h,
    _Float16* __restrict__ w2T,    _Float16* __restrict__ w3h,
    float* __restrict__ coords /* = d_out */) {
    __shared__ float z4[4][128];
    __shared__ float c1s[4][64];
    const int tid = threadIdx.x;
    const int r0  = blockIdx.x * 4;

    // w2T fill (permuted rows): blocks 0..31, 256 elems each.
    if (blockIdx.x < 32) {
        int e = blockIdx.x * 256 + tid;          // e = d*128 + k
        int d = e >> 7, k = e & 127;
        int R = ((d >> 5) & 1) * 32 + ((d >> 2) & 1) * 16 +
                ((d >> 3) & 3) * 4  + (d & 3);
        w2T[R * 128 + k] = (_Float16)eW2[k * 64 + d];
    }
    if (blockIdx.x == 32 && tid < 64) w3h[tid] = (_Float16)eW3[tid];

#pragma unroll
    for (int s = 0; s < 2; ++s) {
        int e = tid + 256 * s;                   // 0..511
        z4[e >> 7][e & 127] = z[r0 * HN + e];
    }
    __syncthreads();

    const int col = tid & 127, which = tid >> 7;   // 0 = pi, 1 = pj
    const float* w = eW1 + which * HN * HN + col;
    float acc4[4] = {0.f, 0.f, 0.f, 0.f};
    for (int k = 0; k < HN; ++k) {
        float wv = w[k * HN];
#pragma unroll
        for (int r = 0; r < 4; ++r) acc4[r] = fmaf(z4[r][k], wv, acc4[r]);
    }
    if (which == 0) {
        float b = eb1[col];
#pragma unroll
        for (int r = 0; r < 4; ++r)
            pi_h[(r0 + r) * HN + col] = (_Float16)(acc4[r] + b);
    } else {
#pragma unroll
        for (int r = 0; r < 4; ++r)
            pj_h[(r0 + r) * HN + col] = (_Float16)acc4[r];
    }

    // coords: c1 = gelu(z @ cW1 + cb1), coords = c1 @ cW2 + cb2
    {
        int row = tid >> 6, mid = tid & 63;      // 256 tasks = 4 rows x 64 mids
        float a = cb1[mid];
        for (int k = 0; k < HN; ++k) a = fmaf(z4[row][k], cW1[k * 64 + mid], a);
        c1s[row][mid] = gelu_f(a);
    }
    __syncthreads();
    if (tid < 8) {
        int row = tid >> 1, o = tid & 1;
        float a = cb2[o];
#pragma unroll 8
        for (int m = 0; m < 64; ++m) a = fmaf(c1s[row][m], cW2[m * 2 + o], a);
        coords[(r0 + row) * 2 + o] = a;
    }
}

// ---------------- Kernel B: fused h1->h2->adj_raw over a 32x32 (i,j) tile ----
// 512 threads (8 waves), each wave does 4 i-rows x 32 j. ONLY w2 lives in LDS
// (16 KB). pi rows are wave-uniform global reads (L1/L2-hot); pj fragments are
// loaded from global once into registers. (512,4): persistent state ~110 VGPR.
// Grid 1024 blocks = exactly 2 rounds at 2 blocks/CU. Measured plateau: this
// config is issue-slot-bound (VALU 66 + MFMA 11 + DS/VMEM issue ~ saturation);
// occupancy lever refuted (R11: +70% occ -> -12% perf), gelu lowering refuted
// twice (R3 poly neutral, R8 asm-pk spill).
__global__ __launch_bounds__(512, 4) void edge_kernel(
    const _Float16* __restrict__ pi_h, const _Float16* __restrict__ pj_h,
    const _Float16* __restrict__ w2T,  const _Float16* __restrict__ w3h,
    const float* __restrict__ eb2,     const float* __restrict__ eb3,
    float* __restrict__ out_adj) {
    __shared__ __align__(16) unsigned int w2_s[64 * 64];  // 16 KB [64 slots][64 dw]
    const int i0 = blockIdx.y * 32, j0 = blockIdx.x * 32;
    const int tid = threadIdx.x;

    const unsigned int* piu = (const unsigned int*)pi_h;   // [1024][64]
    const unsigned int* pju = (const unsigned int*)pj_h;
    const unsigned int* w2u = (const unsigned int*)w2T;    // [64][64]

    // stage w2 swizzled: dword ^= (row&7)<<2; 2 x dwordx4 per thread
#pragma unroll
    for (int s = 0; s < 2; ++s) {
        int e = tid * 4 + 2048 * s;       // dword idx, %4 == 0
        int r = e >> 6;
        uint4 v = *reinterpret_cast<const uint4*>(&w2u[e]);
        *reinterpret_cast<uint4*>(&w2_s[e ^ ((r & 7) << 2)]) = v;
    }

    const int lane = tid & 63;
    const int wave = tid >> 6;          // 0..7
    const int lrow = lane & 15;         // j within subtile / MFMA col
    const int lhi  = lane >> 4;         // k-slice group
    const int lhi4 = lhi << 2;
    const int lhi8 = lhi << 3;
    const int swzW = (lrow & 7) << 2;

    // pj fragments straight from global (t-invariant): 2 j-subtiles x 4 q
    const unsigned int* pjA = &pju[(j0 + lrow) * 64];
    const unsigned int* pjB = &pju[(j0 + 16 + lrow) * 64];
    half8v bA[4], bB[4];
#pragma unroll
    for (int q = 0; q < 4; ++q) {
        const int ko = (q << 4) | lhi4;
        bA[q] = *reinterpret_cast<const half8v*>(&pjA[ko]);
        bB[q] = *reinterpret_cast<const half8v*>(&pjB[ko]);
    }
    const unsigned int* w2base = &w2_s[lrow << 6];

    // w3 A-fragments and permuted-slot eb2 bias (lhi-dependent only)
    const half8v w3f0 = *reinterpret_cast<const half8v*>(&w3h[lhi8]);
    const half8v w3f1 = *reinterpret_cast<const half8v*>(&w3h[32 + lhi8]);
    const float4 e0 = *reinterpret_cast<const float4*>(&eb2[lhi8]);
    const float4 e1 = *reinterpret_cast<const float4*>(&eb2[lhi8 + 4]);
    const float4 e2 = *reinterpret_cast<const float4*>(&eb2[32 + lhi8]);
    const float4 e3 = *reinterpret_cast<const float4*>(&eb2[36 + lhi8]);
    const float b3 = eb3[0];
    __syncthreads();

#pragma unroll
    for (int t = 0; t < 4; ++t) {
        const int iL = (wave << 2) + t;             // 0..31
        const unsigned int* pirow = &piu[(size_t)(i0 + iL) * 64];

        floatx4 accA[4], accB[4];
        accA[0] = (floatx4){e0.x, e0.y, e0.z, e0.w};
        accA[1] = (floatx4){e1.x, e1.y, e1.z, e1.w};
        accA[2] = (floatx4){e2.x, e2.y, e2.z, e2.w};
        accA[3] = (floatx4){e3.x, e3.y, e3.z, e3.w};
#pragma unroll
        for (int c = 0; c < 4; ++c) accB[c] = accA[c];

#pragma unroll
        for (int q = 0; q < 4; ++q) {
            const int ko = (q << 4) | lhi4;
            half8v a = *reinterpret_cast<const half8v*>(&pirow[ko]);  // global

            uint4 sA = __builtin_bit_cast(uint4, a + bA[q]);   // v_pk_add_f16
            uint4 gA;
            gA.x = gelu2u(sA.x); gA.y = gelu2u(sA.y);
            gA.z = gelu2u(sA.z); gA.w = gelu2u(sA.w);
            half8v afA = __builtin_bit_cast(half8v, gA);

            uint4 sB = __builtin_bit_cast(uint4, a + bB[q]);
            uint4 gB;
            gB.x = gelu2u(sB.x); gB.y = gelu2u(sB.y);
            gB.z = gelu2u(sB.z); gB.w = gelu2u(sB.w);
            half8v afB = __builtin_bit_cast(half8v, gB);

            const int kw = ko ^ swzW;
#pragma unroll
            for (int c = 0; c < 4; ++c) {
                half8v bf = *reinterpret_cast<const half8v*>(
                    &w2base[(c << 10) + kw]);       // w2 slot-row c*16+lrow
                accA[c] = __builtin_amdgcn_mfma_f32_16x16x32_f16(
                    bf, afA, accA[c], 0, 0, 0);
                accB[c] = __builtin_amdgcn_mfma_f32_16x16x32_f16(
                    bf, afB, accB[c], 0, 0, 0);
            }
        }

        const float dA = dotw3(accA, w3f0, w3f1, b3);
        const float dB = dotw3(accB, w3f0, w3f1, b3);
        if (lhi == 0) {
            float* row = &out_adj[(size_t)(i0 + iL) * KN + j0];
            row[lrow]      = dA;
            row[16 + lrow] = dB;
        }
    }
}

// ---------------- Kernel C: in-place symmetrize ------------------------------
__global__ __launch_bounds__(256) void sym_kernel(float* __restrict__ adj) {
    int idx = blockIdx.x * 256 + threadIdx.x;
    int i = idx >> 10, j = idx & 1023;
    if (j < i) return;
    float a = adj[i * KN + j];
    float b = adj[j * KN + i];
    float m = 0.5f * (a + b);
    adj[i * KN + j] = m;
    adj[j * KN + i] = m;
}

extern "C" void kernel_launch(void* const* d_in, const int* in_sizes, int n_in,
                              void* d_out, int out_size, void* d_ws, size_t ws_size,
                              hipStream_t stream) {
    const float* z   = (const float*)d_in[0];
    const float* cW1 = (const float*)d_in[1];
    const float* cb1 = (const float*)d_in[2];
    const float* cW2 = (const float*)d_in[3];
    const float* cb2 = (const float*)d_in[4];
    const float* eW1 = (const float*)d_in[5];
    const float* eb1 = (const float*)d_in[6];
    const float* eW2 = (const float*)d_in[7];
    const float* eb2 = (const float*)d_in[8];
    const float* eW3 = (const float*)d_in[9];
    const float* eb3 = (const float*)d_in[10];

    float* out = (float*)d_out;
    _Float16* pi_h = (_Float16*)d_ws;            // [1024][128] f16
    _Float16* pj_h = pi_h + KN * HN;             // [1024][128] f16
    _Float16* w2T  = pj_h + KN * HN;             // [64][128]  f16 (permuted eW2^T)
    _Float16* w3h  = w2T + 64 * HN;              // [64]       f16

    prep_kernel<<<256, 256, 0, stream>>>(z, cW1, cb1, cW2, cb2, eW1, eb1, eW2,
                                         eW3, pi_h, pj_h, w2T, w3h, out);

    dim3 gridB(32, 32);   // x: 32-wide j tiles, y: 32-tall i tiles
    edge_kernel<<<gridB, 512, 0, stream>>>(pi_h, pj_h, w2T, w3h, eb2, eb3,
                                           out + 2048);

    sym_kernel<<<4096, 256, 0, stream>>>(out + 2048);
}

// Round 13
// 75.516 us; speedup vs baseline: 1.1659x; 1.0457x over previous
//
#include <hip/hip_runtime.h>
#include <hip/hip_fp16.h>

// NonAutoregressiveDecoder: K=1024, H=128, fp32 I/O.
// out = (coords_pred [1024,2], adj_logits [1024,1024]) flat-concat.

#define KN 1024
#define HN 128

typedef float  floatx4 __attribute__((ext_vector_type(4)));
typedef _Float16 half8v __attribute__((ext_vector_type(8)));

// f32 GELU (tanh form, log2e folded): x / (1 + exp2(x*(-2.3022087 - 0.1029434 x^2)))
__device__ __forceinline__ float gelu_f(float x) {
    float x2 = x * x;
    float t  = fmaf(x2, -0.1029434f, -2.3022087f);
    float e  = __builtin_amdgcn_exp2f(x * t);
    return x * __builtin_amdgcn_rcpf(e + 1.0f);
}

// packed-f16 GELU on 2 elements held in a uint
__device__ __forceinline__ unsigned int gelu2u(unsigned int xu) {
    __half2 x  = __builtin_bit_cast(__half2, xu);
    __half2 x2 = __hmul2(x, x);
    __half2 t  = __hfma2(x2, __float2half2_rn(-0.1029434f),
                             __float2half2_rn(-2.3022087f));
    __half2 e  = h2exp2(__hmul2(x, t));
    __half2 r  = h2rcp(__hadd2(e, __float2half2_rn(1.0f)));
    return __builtin_bit_cast(unsigned int, __hmul2(x, r));
}

__device__ __forceinline__ unsigned int cvt2u(float a, float b) {
    return __builtin_bit_cast(unsigned int, __builtin_amdgcn_cvt_pkrtz(a, b));
}

// gelu(h2-slots) -> second-MFMA dot with w3: returns adj value (row 0 of D)
__device__ __forceinline__ float dotw3(const floatx4* acc, half8v w3f0,
                                       half8v w3f1, float b3) {
    uint4 u0, u1;
    u0.x = gelu2u(cvt2u(acc[0][0], acc[0][1]));
    u0.y = gelu2u(cvt2u(acc[0][2], acc[0][3]));
    u0.z = gelu2u(cvt2u(acc[1][0], acc[1][1]));
    u0.w = gelu2u(cvt2u(acc[1][2], acc[1][3]));
    u1.x = gelu2u(cvt2u(acc[2][0], acc[2][1]));
    u1.y = gelu2u(cvt2u(acc[2][2], acc[2][3]));
    u1.z = gelu2u(cvt2u(acc[3][0], acc[3][1]));
    u1.w = gelu2u(cvt2u(acc[3][2], acc[3][3]));
    half8v h20 = __builtin_bit_cast(half8v, u0);
    half8v h21 = __builtin_bit_cast(half8v, u1);
    floatx4 d = (floatx4){b3, b3, b3, b3};
    d = __builtin_amdgcn_mfma_f32_16x16x32_f16(w3f0, h20, d, 0, 0, 0);
    d = __builtin_amdgcn_mfma_f32_16x16x32_f16(w3f1, h21, d, 0, 0, 0);
    return d[0];
}

// ---------------- Kernel A: pi' = z@eW1[:H]+eb1 (f16), pj = z@eW1[H:] (f16),
//   coords -> d_out, w2T (f16, dim-PERMUTED transpose of eW2), w3h (f16 eW3) --
// 256 blocks x 256 thr, 4 rows/block (full CU coverage) — R12's verified prep.
// w2T row R(d) = 32*(d>>5)+16*((d>>2)&1)+4*((d>>3)&3)+(d&3).
__global__ __launch_bounds__(256) void prep_kernel(
    const float* __restrict__ z,   const float* __restrict__ cW1,
    const float* __restrict__ cb1, const float* __restrict__ cW2,
    const float* __restrict__ cb2, const float* __restrict__ eW1,
    const float* __restrict__ eb1, const float* __restrict__ eW2,
    const float* __restrict__ eW3,
    _Float16* __restrict__ pi_h,   _Float16* __restrict__ pj_h,
    _Float16* __restrict__ w2T,    _Float16* __restrict__ w3h,
    float* __restrict__ coords /* = d_out */) {
    __shared__ float z4[4][128];
    __shared__ float c1s[4][64];
    const int tid = threadIdx.x;
    const int r0  = blockIdx.x * 4;

    // w2T fill (permuted rows): blocks 0..31, 256 elems each.
    if (blockIdx.x < 32) {
        int e = blockIdx.x * 256 + tid;          // e = d*128 + k
        int d = e >> 7, k = e & 127;
        int R = ((d >> 5) & 1) * 32 + ((d >> 2) & 1) * 16 +
                ((d >> 3) & 3) * 4  + (d & 3);
        w2T[R * 128 + k] = (_Float16)eW2[k * 64 + d];
    }
    if (blockIdx.x == 32 && tid < 64) w3h[tid] = (_Float16)eW3[tid];

#pragma unroll
    for (int s = 0; s < 2; ++s) {
        int e = tid + 256 * s;                   // 0..511
        z4[e >> 7][e & 127] = z[r0 * HN + e];
    }
    __syncthreads();

    const int col = tid & 127, which = tid >> 7;   // 0 = pi, 1 = pj
    const float* w = eW1 + which * HN * HN + col;
    float acc4[4] = {0.f, 0.f, 0.f, 0.f};
    for (int k = 0; k < HN; ++k) {
        float wv = w[k * HN];
#pragma unroll
        for (int r = 0; r < 4; ++r) acc4[r] = fmaf(z4[r][k], wv, acc4[r]);
    }
    if (which == 0) {
        float b = eb1[col];
#pragma unroll
        for (int r = 0; r < 4; ++r)
            pi_h[(r0 + r) * HN + col] = (_Float16)(acc4[r] + b);
    } else {
#pragma unroll
        for (int r = 0; r < 4; ++r)
            pj_h[(r0 + r) * HN + col] = (_Float16)acc4[r];
    }

    // coords: c1 = gelu(z @ cW1 + cb1), coords = c1 @ cW2 + cb2
    {
        int row = tid >> 6, mid = tid & 63;      // 256 tasks = 4 rows x 64 mids
        float a = cb1[mid];
        for (int k = 0; k < HN; ++k) a = fmaf(z4[row][k], cW1[k * 64 + mid], a);
        c1s[row][mid] = gelu_f(a);
    }
    __syncthreads();
    if (tid < 8) {
        int row = tid >> 1, o = tid & 1;
        float a = cb2[o];
#pragma unroll 8
        for (int m = 0; m < 64; ++m) a = fmaf(c1s[row][m], cW2[m * 2 + o], a);
        coords[(r0 + row) * 2 + o] = a;
    }
}

// ---------------- Kernel B: fused h1->h2->adj_raw over a 64x32 (i,j) tile ----
// R5's verified edge (61.0 us, fastest measured): 512 threads (8 waves), each
// wave does 8 i-rows x 32 j. pi/pj/w2 all LDS-staged (40 KB, 1 block/CU —
// occupancy proven irrelevant, kernel is gelu-issue-bound); pj fragments
// hoisted to registers across all 8 t; each w2 LDS read feeds 2 MFMAs.
// LDS XOR-swizzled: dword ^= (row&7)<<2; pi reads have iL&7 == t (static swz).
__global__ __launch_bounds__(512, 4) void edge_kernel(
    const _Float16* __restrict__ pi_h, const _Float16* __restrict__ pj_h,
    const _Float16* __restrict__ w2T,  const _Float16* __restrict__ w3h,
    const float* __restrict__ eb2,     const float* __restrict__ eb3,
    float* __restrict__ out_adj) {
    __shared__ __align__(16) unsigned int pi_s[64 * 64];  // 16 KB [64 rows][64 dw]
    __shared__ __align__(16) unsigned int pj_s[32 * 64];  //  8 KB [32 rows][64 dw]
    __shared__ __align__(16) unsigned int w2_s[64 * 64];  // 16 KB [64 slots][64 dw]
    const int i0 = blockIdx.y * 64, j0 = blockIdx.x * 32;
    const int tid = threadIdx.x;

    const unsigned int* piu = (const unsigned int*)pi_h;   // [1024][64]
    const unsigned int* pju = (const unsigned int*)pj_h;
    const unsigned int* w2u = (const unsigned int*)w2T;    // [64][64]

#pragma unroll
    for (int s = 0; s < 8; ++s) {
        int e = tid + 512 * s;            // 0..4095
        int r = e >> 6;
        pi_s[e ^ ((r & 7) << 2)] = piu[(i0 + r) * 64 + (e & 63)];
    }
#pragma unroll
    for (int s = 0; s < 4; ++s) {
        int e = tid + 512 * s;            // 0..2047
        int r = e >> 6;
        pj_s[e ^ ((r & 7) << 2)] = pju[(j0 + r) * 64 + (e & 63)];
    }
#pragma unroll
    for (int s = 0; s < 8; ++s) {
        int e = tid + 512 * s;            // 0..4095
        int r = e >> 6;
        w2_s[e ^ ((r & 7) << 2)] = w2u[e];
    }

    const int lane = tid & 63;
    const int wave = tid >> 6;          // 0..7
    const int lrow = lane & 15;         // j within subtile / MFMA col
    const int lhi  = lane >> 4;         // k-slice group
    const int lhi4 = lhi << 2;
    const int lhi8 = lhi << 3;
    const int swzJ = (lrow & 7) << 2;

    // w3 A-fragments and permuted-slot eb2 bias (lhi-dependent only)
    const half8v w3f0 = *reinterpret_cast<const half8v*>(&w3h[lhi8]);
    const half8v w3f1 = *reinterpret_cast<const half8v*>(&w3h[32 + lhi8]);
    const float4 e0 = *reinterpret_cast<const float4*>(&eb2[lhi8]);
    const float4 e1 = *reinterpret_cast<const float4*>(&eb2[lhi8 + 4]);
    const float4 e2 = *reinterpret_cast<const float4*>(&eb2[32 + lhi8]);
    const float4 e3 = *reinterpret_cast<const float4*>(&eb2[36 + lhi8]);
    const float b3 = eb3[0];
    __syncthreads();

    // hoist pj fragments (t-invariant): 2 j-subtiles x 4 q
    const unsigned int* pjA = &pj_s[lrow << 6];
    const unsigned int* pjB = &pj_s[(16 + lrow) << 6];   // (16+lrow)&7 == lrow&7
    half8v bA[4], bB[4];
#pragma unroll
    for (int q = 0; q < 4; ++q) {
        const int ko = ((q << 4) | lhi4) ^ swzJ;
        bA[q] = *reinterpret_cast<const half8v*>(&pjA[ko]);
        bB[q] = *reinterpret_cast<const half8v*>(&pjB[ko]);
    }
    const unsigned int* w2base = &w2_s[lrow << 6];

#pragma unroll
    for (int t = 0; t < 8; ++t) {
        const int iL = (wave << 3) + t;             // 0..63, iL&7 == t
        const unsigned int* pirow = &pi_s[iL << 6];
        const int swzI = t << 2;                    // compile-time per t

        floatx4 accA[4], accB[4];
        accA[0] = (floatx4){e0.x, e0.y, e0.z, e0.w};
        accA[1] = (floatx4){e1.x, e1.y, e1.z, e1.w};
        accA[2] = (floatx4){e2.x, e2.y, e2.z, e2.w};
        accA[3] = (floatx4){e3.x, e3.y, e3.z, e3.w};
#pragma unroll
        for (int c = 0; c < 4; ++c) accB[c] = accA[c];

#pragma unroll
        for (int q = 0; q < 4; ++q) {
            const int ko = (q << 4) | lhi4;
            half8v a = *reinterpret_cast<const half8v*>(&pirow[ko ^ swzI]);

            uint4 sA = __builtin_bit_cast(uint4, a + bA[q]);   // v_pk_add_f16
            uint4 gA;
            gA.x = gelu2u(sA.x); gA.y = gelu2u(sA.y);
            gA.z = gelu2u(sA.z); gA.w = gelu2u(sA.w);
            half8v afA = __builtin_bit_cast(half8v, gA);

            uint4 sB = __builtin_bit_cast(uint4, a + bB[q]);
            uint4 gB;
            gB.x = gelu2u(sB.x); gB.y = gelu2u(sB.y);
            gB.z = gelu2u(sB.z); gB.w = gelu2u(sB.w);
            half8v afB = __builtin_bit_cast(half8v, gB);

            const int kw = ko ^ swzJ;
#pragma unroll
            for (int c = 0; c < 4; ++c) {
                half8v bf = *reinterpret_cast<const half8v*>(
                    &w2base[(c << 10) + kw]);       // w2 slot-row c*16+lrow
                accA[c] = __builtin_amdgcn_mfma_f32_16x16x32_f16(
                    bf, afA, accA[c], 0, 0, 0);
                accB[c] = __builtin_amdgcn_mfma_f32_16x16x32_f16(
                    bf, afB, accB[c], 0, 0, 0);
            }
        }

        const float dA = dotw3(accA, w3f0, w3f1, b3);
        const float dB = dotw3(accB, w3f0, w3f1, b3);
        if (lhi == 0) {
            float* row = &out_adj[(size_t)(i0 + iL) * KN + j0];
            row[lrow]      = dA;
            row[16 + lrow] = dB;
        }
    }
}

// ---------------- Kernel C: in-place symmetrize ------------------------------
__global__ __launch_bounds__(256) void sym_kernel(float* __restrict__ adj) {
    int idx = blockIdx.x * 256 + threadIdx.x;
    int i = idx >> 10, j = idx & 1023;
    if (j < i) return;
    float a = adj[i * KN + j];
    float b = adj[j * KN + i];
    float m = 0.5f * (a + b);
    adj[i * KN + j] = m;
    adj[j * KN + i] = m;
}

extern "C" void kernel_launch(void* const* d_in, const int* in_sizes, int n_in,
                              void* d_out, int out_size, void* d_ws, size_t ws_size,
                              hipStream_t stream) {
    const float* z   = (const float*)d_in[0];
    const float* cW1 = (const float*)d_in[1];
    const float* cb1 = (const float*)d_in[2];
    const float* cW2 = (const float*)d_in[3];
    const float* cb2 = (const float*)d_in[4];
    const float* eW1 = (const float*)d_in[5];
    const float* eb1 = (const float*)d_in[6];
    const float* eW2 = (const float*)d_in[7];
    const float* eb2 = (const float*)d_in[8];
    const float* eW3 = (const float*)d_in[9];
    const float* eb3 = (const float*)d_in[10];

    float* out = (float*)d_out;
    _Float16* pi_h = (_Float16*)d_ws;            // [1024][128] f16
    _Float16* pj_h = pi_h + KN * HN;             // [1024][128] f16
    _Float16* w2T  = pj_h + KN * HN;             // [64][128]  f16 (permuted eW2^T)
    _Float16* w3h  = w2T + 64 * HN;              // [64]       f16

    prep_kernel<<<256, 256, 0, stream>>>(z, cW1, cb1, cW2, cb2, eW1, eb1, eW2,
                                         eW3, pi_h, pj_h, w2T, w3h, out);

    dim3 gridB(32, 16);   // x: 32-wide j tiles, y: 64-tall i tiles
    edge_kernel<<<gridB, 512, 0, stream>>>(pi_h, pj_h, w2T, w3h, eb2, eb3,
                                           out + 2048);

    sym_kernel<<<4096, 256, 0, stream>>>(out + 2048);
}